// Round 6
// baseline (220.486 us; speedup 1.0000x reference)
//
#include <hip/hip_runtime.h>

// Problem constants (fixed by reference)
#define D_DIRS 1024
#define P_PTS  256
#define R_RANK 64
#define K_SUB  1024

typedef float v4f __attribute__((ext_vector_type(4)));

// Workspace layout in floats:
//   Msum[64][64] @ 131072 (4096) -- zeroed by hipMemsetAsync before k1;
//                                   atomically accumulated by k1's tail.
// (a/b staging slots are gone: R12 folds the M-accumulation into k1.)
#define WS_MSUM (2 * D_DIRS * R_RANK)

__device__ __forceinline__ v4f ntload(const v4f* __restrict__ p) {
    return __builtin_nontemporal_load(p);
}

__device__ __forceinline__ v4f shfl_xor_v4(v4f v, int m) {
    v4f r;
    r.x = __shfl_xor(v.x, m);
    r.y = __shfl_xor(v.y, m);
    r.z = __shfl_xor(v.z, m);
    r.w = __shfl_xor(v.w, m);
    return r;
}

// ---------------------------------------------------------------------------
// Evidence ledger (k1 streaming, CLOSED): nt ~33-38 us / 4.1 TB/s across 8
// structural variants; cached path 44-48 us in both compiler-collapsed (R2)
// and asm-pipelined (R4) forms; occupancy doubling neutral (R7); cooperative
// fusion catastrophic (+48 us launch overhead, pipeline collapse — R5/R11).
// Remaining budget: ~20-25 us of plain launch gaps across 3 kernels.
//
// R12: fold k2 into k1's tail (2 launches + 1 tiny memset instead of 3
// launches), drop the 512 KB a/b round-trip:
//   - streaming phase: BYTE-IDENTICAL to the R0-proven nt pipeline
//     (512 thr, wave owns (d, half-slab), 8-load chunks 2-deep,
//     shfl_xor 8/16/32 — no barriers).
//   - tail: lanes pr==0 stage a_d,b_d into 2 KiB LDS; one __syncthreads;
//     512 threads compute the block's 4-d 64x64 partial (row = t>>3,
//     8 cols each, 32 FMA/thread; sa reads broadcast, sb reads 2-way =
//     free per bank rules); 8 atomicAdds/thread into Msum.
//     1M atomics total, 256-way/address, spread over block tails (~1 us).
//   - Msum zero-init: hipMemsetAsync on stream (16 KiB) — stream-ordered
//     before k1's atomics; graph-capturable (harness fills are memsets).
// ---------------------------------------------------------------------------
__global__ __launch_bounds__(512) void k_stream_m(const float* __restrict__ atten,
                                                  const float* __restrict__ rad,
                                                  float* __restrict__ ws) {
    const int t    = threadIdx.x;
    const int wave = t >> 6;
    const int lane = t & 63;
    const int d    = blockIdx.x * 4 + (wave >> 1);
    const int half = wave & 1;
    const int r4g  = lane & 7;
    const int pr   = lane >> 3;

    const int base = pr * 16 + half * 8 + r4g; // within-slab float4 offset
    const v4f* A4 = (const v4f*)atten + (size_t)d * 4096 + base;
    const v4f* B4 = (const v4f*)rad   + (size_t)d * 4096 + base;

    v4f pa[8], pb[8], na[8], nb[8];
#pragma unroll
    for (int j = 0; j < 8; ++j) pa[j] = ntload(A4 + j * 128);
#pragma unroll
    for (int j = 0; j < 8; ++j) pb[j] = ntload(B4 + j * 128);

    v4f acc_a = {0.f, 0.f, 0.f, 0.f};
    v4f acc_b = {0.f, 0.f, 0.f, 0.f};

#pragma unroll
    for (int mc = 0; mc < 4; ++mc) {
        if (mc < 3) {
            const int off = (mc + 1) * 8 * 128;
#pragma unroll
            for (int j = 0; j < 8; ++j) na[j] = ntload(A4 + off + j * 128);
#pragma unroll
            for (int j = 0; j < 8; ++j) nb[j] = ntload(B4 + off + j * 128);
        }
        acc_a = acc_a + (((pa[0] + pa[1]) + (pa[2] + pa[3])) +
                         ((pa[4] + pa[5]) + (pa[6] + pa[7])));
        acc_b = acc_b + (((pb[0] + pb[1]) + (pb[2] + pb[3])) +
                         ((pb[4] + pb[5]) + (pb[6] + pb[7])));
#pragma unroll
        for (int j = 0; j < 8; ++j) { pa[j] = na[j]; pb[j] = nb[j]; }
    }

    // Reduce across pr (lanes sharing r4g): xor 8, 16, 32. No barriers.
    acc_a = acc_a + shfl_xor_v4(acc_a, 8);
    acc_a = acc_a + shfl_xor_v4(acc_a, 16);
    acc_a = acc_a + shfl_xor_v4(acc_a, 32);
    acc_b = acc_b + shfl_xor_v4(acc_b, 8);
    acc_b = acc_b + shfl_xor_v4(acc_b, 16);
    acc_b = acc_b + shfl_xor_v4(acc_b, 32);

    // ---- R12 tail: block-local 4-d outer-product partial + atomics ----
    __shared__ float sa[4][64]; // 1 KiB
    __shared__ float sb[4][64]; // 1 KiB

    const int wp = wave >> 1; // d-slot within block, 0..3
    if (pr == 0) { // lanes 0..7 hold the reduced v4f for r = 4*(half*8+r4g)
        *(v4f*)&sa[wp][(half * 8 + r4g) * 4] = acc_a;
        *(v4f*)&sb[wp][(half * 8 + r4g) * 4] = acc_b;
    }
    __syncthreads();

    const int row = t >> 3;       // 0..63
    const int cb  = (t & 7) * 8;  // col base, 8 cols per thread

    float acc[8];
#pragma unroll
    for (int j = 0; j < 8; ++j) acc[j] = 0.f;

#pragma unroll
    for (int dd = 0; dd < 4; ++dd) {
        const float av = sa[dd][row];                      // broadcast
        const float4 b0 = *(const float4*)&sb[dd][cb];     // 2-way, free
        const float4 b1 = *(const float4*)&sb[dd][cb + 4];
        acc[0] += av * b0.x; acc[1] += av * b0.y;
        acc[2] += av * b0.z; acc[3] += av * b0.w;
        acc[4] += av * b1.x; acc[5] += av * b1.y;
        acc[6] += av * b1.z; acc[7] += av * b1.w;
    }

    float* Msum = ws + WS_MSUM;
#pragma unroll
    for (int j = 0; j < 8; ++j)
        atomicAdd(&Msum[row * 64 + cb + j], acc[j]);
}

// ---------------------------------------------------------------------------
// Kernel 3: csi[k] = (1/D) F[k] Msum F[k]^T.  UNCHANGED (proven form).
// 16 blocks x 256 threads; block bb owns k in [bb*64, bb*64+64).
// Fs padded stride 65 -> conflict-free; Ms reads are wave-uniform broadcasts.
// ---------------------------------------------------------------------------
__global__ __launch_bounds__(256) void k_csi(const float* __restrict__ ws,
                                             const float* __restrict__ freq,
                                             float* __restrict__ out) {
    const int bb = blockIdx.x;
    const int t  = threadIdx.x;

    __shared__ float Ms[64 * 68];   // ~17 KiB
    __shared__ float Fs[64 * 65];   // ~16.6 KiB
    __shared__ float red[4][64];

    const float4* M4 = (const float4*)(ws + WS_MSUM);
#pragma unroll
    for (int i = 0; i < 4; ++i) {
        const int idx4 = i * 256 + t;
        const float4 s = M4[idx4];
        const int r = idx4 >> 4, c4 = idx4 & 15;
        *(float4*)&Ms[r * 68 + c4 * 4] = s;
    }

    const float4* F4 = (const float4*)freq + bb * 1024;
#pragma unroll
    for (int i = 0; i < 4; ++i) {
        const int idx4 = i * 256 + t;
        const float4 v = F4[idx4];
        const int row = idx4 >> 4, c4 = idx4 & 15;
        Fs[row * 65 + c4 * 4 + 0] = v.x;
        Fs[row * 65 + c4 * 4 + 1] = v.y;
        Fs[row * 65 + c4 * 4 + 2] = v.z;
        Fs[row * 65 + c4 * 4 + 3] = v.w;
    }
    __syncthreads();

    const int kl = t & 63;
    const int jg = t >> 6;

    float h[16];
#pragma unroll
    for (int j = 0; j < 16; ++j) h[j] = 0.f;

    for (int r = 0; r < 64; ++r) {
        const float fv = Fs[kl * 65 + r];
        const float4* mr = (const float4*)&Ms[r * 68 + jg * 16];
        const float4 m0 = mr[0], m1 = mr[1], m2 = mr[2], m3 = mr[3];
        h[0]  += fv * m0.x; h[1]  += fv * m0.y; h[2]  += fv * m0.z; h[3]  += fv * m0.w;
        h[4]  += fv * m1.x; h[5]  += fv * m1.y; h[6]  += fv * m1.z; h[7]  += fv * m1.w;
        h[8]  += fv * m2.x; h[9]  += fv * m2.y; h[10] += fv * m2.z; h[11] += fv * m2.w;
        h[12] += fv * m3.x; h[13] += fv * m3.y; h[14] += fv * m3.z; h[15] += fv * m3.w;
    }

    float part = 0.f;
#pragma unroll
    for (int j = 0; j < 16; ++j) part += h[j] * Fs[kl * 65 + jg * 16 + j];

    red[jg][kl] = part;
    __syncthreads();
    if (t < 64) {
        out[bb * 64 + t] =
            (red[0][t] + red[1][t] + red[2][t] + red[3][t]) * (1.0f / (float)D_DIRS);
    }
}

extern "C" void kernel_launch(void* const* d_in, const int* in_sizes, int n_in,
                              void* d_out, int out_size, void* d_ws, size_t ws_size,
                              hipStream_t stream) {
    const float* atten = (const float*)d_in[0]; // (D,P,R)
    const float* rad   = (const float*)d_in[1]; // (D,P,R)
    const float* freq  = (const float*)d_in[2]; // (K,R)
    float* out = (float*)d_out;                 // (K,)
    float* ws  = (float*)d_ws;                  // needs 528 KiB

    // Zero Msum (16 KiB) — stream-ordered before k_stream_m's atomics.
    hipMemsetAsync(ws + WS_MSUM, 0, R_RANK * R_RANK * sizeof(float), stream);
    k_stream_m<<<D_DIRS / 4, 512, 0, stream>>>(atten, rad, ws);
    k_csi<<<16, 256, 0, stream>>>(ws, freq, out);
}

// Round 7
// 149.986 us; speedup vs baseline: 1.4700x; 1.4700x over previous
//
#include <hip/hip_runtime.h>

// Problem constants (fixed by reference)
#define D_DIRS 1024
#define P_PTS  256
#define R_RANK 64
#define K_SUB  1024

typedef float v4f __attribute__((ext_vector_type(4)));

// Workspace layout in floats:
//   a[D][R]          @ 0      (65536)
//   b[D][R]          @ 65536  (65536)
//   Msum[4][64][64]  @ 131072 (16384) -- 4 replicas, zeroed by k1 block 0,
//                                        k2 block bb accumulates replica
//                                        bb&3, k3 sums the 4 during staging.
// R13: replication cuts per-line atomic contention 512->128 RMWs (R6's
// counter calibration: contended same-line RMW ~14ns, serialized per line;
// R0's single-Msum k2 carried ~7us of atomic drain).
#define WS_A 0
#define WS_B (D_DIRS * R_RANK)
#define WS_MSUM (2 * D_DIRS * R_RANK)
#define NREP 4
#define NB_B 32
#define DCHUNK (D_DIRS / NB_B) // 32

__device__ __forceinline__ v4f ntload(const v4f* __restrict__ p) {
    return __builtin_nontemporal_load(p);
}

__device__ __forceinline__ v4f shfl_xor_v4(v4f v, int m) {
    v4f r;
    r.x = __shfl_xor(v.x, m);
    r.y = __shfl_xor(v.y, m);
    r.z = __shfl_xor(v.z, m);
    r.w = __shfl_xor(v.w, m);
    return r;
}

// ---------------------------------------------------------------------------
// Kernel 1: p-reduction.  a[d,r] = sum_p atten[d,p,r]; b likewise.
// R0-proven structure, BYTE-IDENTICAL streaming loop (33-35 us, 4.1 TB/s —
// best of 8 variants over 2 sessions; ledger CLOSED: cached path slower in
// both compiler-collapsed and asm-pipelined forms, occupancy doubling
// neutral, fusion of any kind collapses the pipeline). Block 0 zeroes the
// 4 Msum replicas (16 KiB; same pattern R0 used for 4 KiB).
// ---------------------------------------------------------------------------
__global__ __launch_bounds__(512) void k_reduce_p(const float* __restrict__ atten,
                                                  const float* __restrict__ rad,
                                                  float* __restrict__ ws) {
    const int t    = threadIdx.x;
    const int wave = t >> 6;
    const int lane = t & 63;
    const int d    = blockIdx.x * 4 + (wave >> 1);
    const int half = wave & 1;
    const int r4g  = lane & 7;
    const int pr   = lane >> 3;

    if (blockIdx.x == 0) { // zero 4 Msum replicas: 512 thr x 8 float4
        v4f z = {0.f, 0.f, 0.f, 0.f};
#pragma unroll
        for (int i = 0; i < 8; ++i)
            ((v4f*)(ws + WS_MSUM))[t + i * 512] = z;
    }

    const int base = pr * 16 + half * 8 + r4g; // within-slab float4 offset, c=0
    const v4f* A4 = (const v4f*)atten + (size_t)d * 4096 + base;
    const v4f* B4 = (const v4f*)rad   + (size_t)d * 4096 + base;

    v4f pa[8], pb[8], na[8], nb[8];
#pragma unroll
    for (int j = 0; j < 8; ++j) pa[j] = ntload(A4 + j * 128);
#pragma unroll
    for (int j = 0; j < 8; ++j) pb[j] = ntload(B4 + j * 128);

    v4f acc_a = {0.f, 0.f, 0.f, 0.f};
    v4f acc_b = {0.f, 0.f, 0.f, 0.f};

#pragma unroll
    for (int mc = 0; mc < 4; ++mc) {
        if (mc < 3) {
            const int off = (mc + 1) * 8 * 128;
#pragma unroll
            for (int j = 0; j < 8; ++j) na[j] = ntload(A4 + off + j * 128);
#pragma unroll
            for (int j = 0; j < 8; ++j) nb[j] = ntload(B4 + off + j * 128);
        }
        acc_a = acc_a + (((pa[0] + pa[1]) + (pa[2] + pa[3])) +
                         ((pa[4] + pa[5]) + (pa[6] + pa[7])));
        acc_b = acc_b + (((pb[0] + pb[1]) + (pb[2] + pb[3])) +
                         ((pb[4] + pb[5]) + (pb[6] + pb[7])));
#pragma unroll
        for (int j = 0; j < 8; ++j) { pa[j] = na[j]; pb[j] = nb[j]; }
    }

    // Reduce across pr (lanes sharing r4g): xor 8, 16, 32. No barriers.
    acc_a = acc_a + shfl_xor_v4(acc_a, 8);
    acc_a = acc_a + shfl_xor_v4(acc_a, 16);
    acc_a = acc_a + shfl_xor_v4(acc_a, 32);
    acc_b = acc_b + shfl_xor_v4(acc_b, 8);
    acc_b = acc_b + shfl_xor_v4(acc_b, 16);
    acc_b = acc_b + shfl_xor_v4(acc_b, 32);

    if (pr == 0) { // lanes 0..7
        ((v4f*)(ws + WS_A))[d * 16 + half * 8 + r4g] = acc_a;
        ((v4f*)(ws + WS_B))[d * 16 + half * 8 + r4g] = acc_b;
    }
}

// ---------------------------------------------------------------------------
// Kernel 2: M accumulation.  Block bb covers d in [bb*32, bb*32+32); computes
// its 64x64 partial in registers then atomicAdds into replica bb&3.
// R13 change vs R0: replica target only — per-line contention 512->128 RMWs.
// fp32 reassociation well inside absmax threshold (1.0 vs 37.8).
// ---------------------------------------------------------------------------
__global__ __launch_bounds__(256) void k_partial_m(float* __restrict__ ws) {
    const int bb = blockIdx.x;
    const int t  = threadIdx.x;

    __shared__ float sa[DCHUNK * R_RANK]; // 8 KiB
    __shared__ float sb[DCHUNK * R_RANK]; // 8 KiB

    const float4* a4 = (const float4*)(ws + WS_A) + bb * (DCHUNK * R_RANK / 4);
    const float4* b4 = (const float4*)(ws + WS_B) + bb * (DCHUNK * R_RANK / 4);
    float4* sa4 = (float4*)sa;
    float4* sb4 = (float4*)sb;
    sa4[t]       = a4[t];
    sa4[t + 256] = a4[t + 256];
    sb4[t]       = b4[t];
    sb4[t + 256] = b4[t + 256];
    __syncthreads();

    const int c  = t & 63;
    const int wg = t >> 6;

    float acc[16];
#pragma unroll
    for (int i = 0; i < 16; ++i) acc[i] = 0.f;

    for (int dd = 0; dd < DCHUNK; ++dd) {
        const float bv = sb[dd * 64 + c];
        const float4* ar = (const float4*)&sa[dd * 64 + wg * 16];
        const float4 a0 = ar[0], a1 = ar[1], a2 = ar[2], a3 = ar[3];
        acc[0]  += a0.x * bv; acc[1]  += a0.y * bv; acc[2]  += a0.z * bv; acc[3]  += a0.w * bv;
        acc[4]  += a1.x * bv; acc[5]  += a1.y * bv; acc[6]  += a1.z * bv; acc[7]  += a1.w * bv;
        acc[8]  += a2.x * bv; acc[9]  += a2.y * bv; acc[10] += a2.z * bv; acc[11] += a2.w * bv;
        acc[12] += a3.x * bv; acc[13] += a3.y * bv; acc[14] += a3.z * bv; acc[15] += a3.w * bv;
    }

    float* Msum = ws + WS_MSUM + (bb & (NREP - 1)) * (R_RANK * R_RANK);
#pragma unroll
    for (int i = 0; i < 16; ++i)
        atomicAdd(&Msum[(wg * 16 + i) * 64 + c], acc[i]);
}

// ---------------------------------------------------------------------------
// Kernel 3: csi[k] = (1/D) F[k] M F[k]^T, M = sum of the 4 replicas (summed
// during Ms staging: 4 independent L2-resident loads per entry — hidden).
// Otherwise the R0-proven form: 16 blocks x 256 threads, Fs stride 65,
// Ms reads wave-uniform broadcasts.
// ---------------------------------------------------------------------------
__global__ __launch_bounds__(256) void k_csi(const float* __restrict__ ws,
                                             const float* __restrict__ freq,
                                             float* __restrict__ out) {
    const int bb = blockIdx.x;
    const int t  = threadIdx.x;

    __shared__ float Ms[64 * 68];   // ~17 KiB
    __shared__ float Fs[64 * 65];   // ~16.6 KiB
    __shared__ float red[4][64];

    const float4* M4 = (const float4*)(ws + WS_MSUM);
#pragma unroll
    for (int i = 0; i < 4; ++i) {
        const int idx4 = i * 256 + t;
        const float4 v0 = M4[idx4];
        const float4 v1 = M4[idx4 + 1024];
        const float4 v2 = M4[idx4 + 2048];
        const float4 v3 = M4[idx4 + 3072];
        float4 s;
        s.x = (v0.x + v1.x) + (v2.x + v3.x);
        s.y = (v0.y + v1.y) + (v2.y + v3.y);
        s.z = (v0.z + v1.z) + (v2.z + v3.z);
        s.w = (v0.w + v1.w) + (v2.w + v3.w);
        const int r = idx4 >> 4, c4 = idx4 & 15;
        *(float4*)&Ms[r * 68 + c4 * 4] = s;
    }

    const float4* F4 = (const float4*)freq + bb * 1024;
#pragma unroll
    for (int i = 0; i < 4; ++i) {
        const int idx4 = i * 256 + t;
        const float4 v = F4[idx4];
        const int row = idx4 >> 4, c4 = idx4 & 15;
        Fs[row * 65 + c4 * 4 + 0] = v.x;
        Fs[row * 65 + c4 * 4 + 1] = v.y;
        Fs[row * 65 + c4 * 4 + 2] = v.z;
        Fs[row * 65 + c4 * 4 + 3] = v.w;
    }
    __syncthreads();

    const int kl = t & 63;
    const int jg = t >> 6;

    float h[16];
#pragma unroll
    for (int j = 0; j < 16; ++j) h[j] = 0.f;

    for (int r = 0; r < 64; ++r) {
        const float fv = Fs[kl * 65 + r];
        const float4* mr = (const float4*)&Ms[r * 68 + jg * 16];
        const float4 m0 = mr[0], m1 = mr[1], m2 = mr[2], m3 = mr[3];
        h[0]  += fv * m0.x; h[1]  += fv * m0.y; h[2]  += fv * m0.z; h[3]  += fv * m0.w;
        h[4]  += fv * m1.x; h[5]  += fv * m1.y; h[6]  += fv * m1.z; h[7]  += fv * m1.w;
        h[8]  += fv * m2.x; h[9]  += fv * m2.y; h[10] += fv * m2.z; h[11] += fv * m2.w;
        h[12] += fv * m3.x; h[13] += fv * m3.y; h[14] += fv * m3.z; h[15] += fv * m3.w;
    }

    float part = 0.f;
#pragma unroll
    for (int j = 0; j < 16; ++j) part += h[j] * Fs[kl * 65 + jg * 16 + j];

    red[jg][kl] = part;
    __syncthreads();
    if (t < 64) {
        out[bb * 64 + t] =
            (red[0][t] + red[1][t] + red[2][t] + red[3][t]) * (1.0f / (float)D_DIRS);
    }
}

extern "C" void kernel_launch(void* const* d_in, const int* in_sizes, int n_in,
                              void* d_out, int out_size, void* d_ws, size_t ws_size,
                              hipStream_t stream) {
    const float* atten = (const float*)d_in[0]; // (D,P,R)
    const float* rad   = (const float*)d_in[1]; // (D,P,R)
    const float* freq  = (const float*)d_in[2]; // (K,R)
    float* out = (float*)d_out;                 // (K,)
    float* ws  = (float*)d_ws;                  // needs 576 KiB

    k_reduce_p<<<D_DIRS / 4, 512, 0, stream>>>(atten, rad, ws);
    k_partial_m<<<NB_B, 256, 0, stream>>>(ws);
    k_csi<<<16, 256, 0, stream>>>(ws, freq, out);
}

// Round 8
// 147.839 us; speedup vs baseline: 1.4914x; 1.0145x over previous
//
#include <hip/hip_runtime.h>

// Problem constants (fixed by reference)
#define D_DIRS 1024
#define P_PTS  256
#define R_RANK 64
#define K_SUB  1024

typedef float v4f __attribute__((ext_vector_type(4)));

// Workspace layout in floats:
//   a[D][R]      @ 0        (65536)
//   b[D][R]      @ 65536    (65536)
//   Msum[64][64] @ 131072   (4096)   -- zeroed by k1 block 0, atomically
//                                       accumulated by k_partial_m.
#define WS_A 0
#define WS_B (D_DIRS * R_RANK)
#define WS_MSUM (2 * D_DIRS * R_RANK)
#define NB_B 32
#define DCHUNK (D_DIRS / NB_B) // 32

__device__ __forceinline__ v4f ntload(const v4f* __restrict__ p) {
    return __builtin_nontemporal_load(p);
}

__device__ __forceinline__ v4f shfl_xor_v4(v4f v, int m) {
    v4f r;
    r.x = __shfl_xor(v.x, m);
    r.y = __shfl_xor(v.y, m);
    r.z = __shfl_xor(v.z, m);
    r.w = __shfl_xor(v.w, m);
    return r;
}

// ---------------------------------------------------------------------------
// FINAL (R14 = byte-exact R0 revert). Session ledger:
//   R0 146.95 | R1 occupancy-2x 148.0 | R2 no-nt 155.4 | R3 no-atomics 158.4
//   R4 asm-cached 156.5 | R5 coop-fusion 208.4 | R6 tail-fusion 220.5
//   R7 4-way-replica 150.0
// Closed findings:
//   - nt streaming = 4.1 TB/s ceiling for this read pattern (8 variants);
//     cached path caps ~3.0 TB/s against the harness's 256 MB dirty fills
//     (proven in BOTH compiler-collapsed and asm-pipelined forms).
//   - k1 is not latency/occupancy-bound (2x waves neutral).
//   - k2's atomics are not a cost at 512 RMW/line (replication neutral);
//     contended RMW only explodes ~4K/line (R6: 57 us).
//   - Launch fusion loses: cooperative launch +48 us overhead; de-launch
//     via tail-fold hits the atomic wall.
// Budget at floor: 81 us harness fills + ~35 us k1 @4.1 TB/s + ~30 us
// k2+k3+gaps (three independent structural attacks all regressed).
// ---------------------------------------------------------------------------
__global__ __launch_bounds__(512) void k_reduce_p(const float* __restrict__ atten,
                                                  const float* __restrict__ rad,
                                                  float* __restrict__ ws) {
    const int t    = threadIdx.x;
    const int wave = t >> 6;
    const int lane = t & 63;
    const int d    = blockIdx.x * 4 + (wave >> 1);
    const int half = wave & 1;
    const int r4g  = lane & 7;
    const int pr   = lane >> 3;

    if (blockIdx.x == 0) { // zero Msum: 512 threads x 2 float4 = 4096 floats
        v4f z = {0.f, 0.f, 0.f, 0.f};
        ((v4f*)(ws + WS_MSUM))[t]       = z;
        ((v4f*)(ws + WS_MSUM))[t + 512] = z;
    }

    const int base = pr * 16 + half * 8 + r4g; // within-slab float4 offset, c=0
    const v4f* A4 = (const v4f*)atten + (size_t)d * 4096 + base;
    const v4f* B4 = (const v4f*)rad   + (size_t)d * 4096 + base;

    v4f pa[8], pb[8], na[8], nb[8];
#pragma unroll
    for (int j = 0; j < 8; ++j) pa[j] = ntload(A4 + j * 128);
#pragma unroll
    for (int j = 0; j < 8; ++j) pb[j] = ntload(B4 + j * 128);

    v4f acc_a = {0.f, 0.f, 0.f, 0.f};
    v4f acc_b = {0.f, 0.f, 0.f, 0.f};

#pragma unroll
    for (int mc = 0; mc < 4; ++mc) {
        if (mc < 3) {
            const int off = (mc + 1) * 8 * 128;
#pragma unroll
            for (int j = 0; j < 8; ++j) na[j] = ntload(A4 + off + j * 128);
#pragma unroll
            for (int j = 0; j < 8; ++j) nb[j] = ntload(B4 + off + j * 128);
        }
        acc_a = acc_a + (((pa[0] + pa[1]) + (pa[2] + pa[3])) +
                         ((pa[4] + pa[5]) + (pa[6] + pa[7])));
        acc_b = acc_b + (((pb[0] + pb[1]) + (pb[2] + pb[3])) +
                         ((pb[4] + pb[5]) + (pb[6] + pb[7])));
#pragma unroll
        for (int j = 0; j < 8; ++j) { pa[j] = na[j]; pb[j] = nb[j]; }
    }

    // Reduce across pr (lanes sharing r4g): xor 8, 16, 32. No barriers.
    acc_a = acc_a + shfl_xor_v4(acc_a, 8);
    acc_a = acc_a + shfl_xor_v4(acc_a, 16);
    acc_a = acc_a + shfl_xor_v4(acc_a, 32);
    acc_b = acc_b + shfl_xor_v4(acc_b, 8);
    acc_b = acc_b + shfl_xor_v4(acc_b, 16);
    acc_b = acc_b + shfl_xor_v4(acc_b, 32);

    if (pr == 0) { // lanes 0..7
        ((v4f*)(ws + WS_A))[d * 16 + half * 8 + r4g] = acc_a;
        ((v4f*)(ws + WS_B))[d * 16 + half * 8 + r4g] = acc_b;
    }
}

// ---------------------------------------------------------------------------
// Kernel 2: M accumulation.  Block bb covers d in [bb*32, bb*32+32); computes
// its 64x64 partial in registers then atomicAdds into Msum (32-way contention
// per address — 131K atomics total, proven-negligible at this level; fp32
// reassociation well inside the absmax threshold: 1.0 vs 37.8).
// ---------------------------------------------------------------------------
__global__ __launch_bounds__(256) void k_partial_m(float* __restrict__ ws) {
    const int bb = blockIdx.x;
    const int t  = threadIdx.x;

    __shared__ float sa[DCHUNK * R_RANK]; // 8 KiB
    __shared__ float sb[DCHUNK * R_RANK]; // 8 KiB

    const float4* a4 = (const float4*)(ws + WS_A) + bb * (DCHUNK * R_RANK / 4);
    const float4* b4 = (const float4*)(ws + WS_B) + bb * (DCHUNK * R_RANK / 4);
    float4* sa4 = (float4*)sa;
    float4* sb4 = (float4*)sb;
    sa4[t]       = a4[t];
    sa4[t + 256] = a4[t + 256];
    sb4[t]       = b4[t];
    sb4[t + 256] = b4[t + 256];
    __syncthreads();

    const int c  = t & 63;
    const int wg = t >> 6;

    float acc[16];
#pragma unroll
    for (int i = 0; i < 16; ++i) acc[i] = 0.f;

    for (int dd = 0; dd < DCHUNK; ++dd) {
        const float bv = sb[dd * 64 + c];
        const float4* ar = (const float4*)&sa[dd * 64 + wg * 16];
        const float4 a0 = ar[0], a1 = ar[1], a2 = ar[2], a3 = ar[3];
        acc[0]  += a0.x * bv; acc[1]  += a0.y * bv; acc[2]  += a0.z * bv; acc[3]  += a0.w * bv;
        acc[4]  += a1.x * bv; acc[5]  += a1.y * bv; acc[6]  += a1.z * bv; acc[7]  += a1.w * bv;
        acc[8]  += a2.x * bv; acc[9]  += a2.y * bv; acc[10] += a2.z * bv; acc[11] += a2.w * bv;
        acc[12] += a3.x * bv; acc[13] += a3.y * bv; acc[14] += a3.z * bv; acc[15] += a3.w * bv;
    }

    float* Msum = ws + WS_MSUM;
#pragma unroll
    for (int i = 0; i < 16; ++i)
        atomicAdd(&Msum[(wg * 16 + i) * 64 + c], acc[i]);
}

// ---------------------------------------------------------------------------
// Kernel 3: csi[k] = (1/D) F[k] Msum F[k]^T.
// 16 blocks x 256 threads; block bb owns k in [bb*64, bb*64+64).
// Fs padded stride 65 -> conflict-free; Ms reads are wave-uniform broadcasts.
// ---------------------------------------------------------------------------
__global__ __launch_bounds__(256) void k_csi(const float* __restrict__ ws,
                                             const float* __restrict__ freq,
                                             float* __restrict__ out) {
    const int bb = blockIdx.x;
    const int t  = threadIdx.x;

    __shared__ float Ms[64 * 68];   // ~17 KiB
    __shared__ float Fs[64 * 65];   // ~16.6 KiB
    __shared__ float red[4][64];

    const float4* M4 = (const float4*)(ws + WS_MSUM);
#pragma unroll
    for (int i = 0; i < 4; ++i) {
        const int idx4 = i * 256 + t;
        const float4 s = M4[idx4];
        const int r = idx4 >> 4, c4 = idx4 & 15;
        *(float4*)&Ms[r * 68 + c4 * 4] = s;
    }

    const float4* F4 = (const float4*)freq + bb * 1024;
#pragma unroll
    for (int i = 0; i < 4; ++i) {
        const int idx4 = i * 256 + t;
        const float4 v = F4[idx4];
        const int row = idx4 >> 4, c4 = idx4 & 15;
        Fs[row * 65 + c4 * 4 + 0] = v.x;
        Fs[row * 65 + c4 * 4 + 1] = v.y;
        Fs[row * 65 + c4 * 4 + 2] = v.z;
        Fs[row * 65 + c4 * 4 + 3] = v.w;
    }
    __syncthreads();

    const int kl = t & 63;
    const int jg = t >> 6;

    float h[16];
#pragma unroll
    for (int j = 0; j < 16; ++j) h[j] = 0.f;

    for (int r = 0; r < 64; ++r) {
        const float fv = Fs[kl * 65 + r];
        const float4* mr = (const float4*)&Ms[r * 68 + jg * 16];
        const float4 m0 = mr[0], m1 = mr[1], m2 = mr[2], m3 = mr[3];
        h[0]  += fv * m0.x; h[1]  += fv * m0.y; h[2]  += fv * m0.z; h[3]  += fv * m0.w;
        h[4]  += fv * m1.x; h[5]  += fv * m1.y; h[6]  += fv * m1.z; h[7]  += fv * m1.w;
        h[8]  += fv * m2.x; h[9]  += fv * m2.y; h[10] += fv * m2.z; h[11] += fv * m2.w;
        h[12] += fv * m3.x; h[13] += fv * m3.y; h[14] += fv * m3.z; h[15] += fv * m3.w;
    }

    float part = 0.f;
#pragma unroll
    for (int j = 0; j < 16; ++j) part += h[j] * Fs[kl * 65 + jg * 16 + j];

    red[jg][kl] = part;
    __syncthreads();
    if (t < 64) {
        out[bb * 64 + t] =
            (red[0][t] + red[1][t] + red[2][t] + red[3][t]) * (1.0f / (float)D_DIRS);
    }
}

extern "C" void kernel_launch(void* const* d_in, const int* in_sizes, int n_in,
                              void* d_out, int out_size, void* d_ws, size_t ws_size,
                              hipStream_t stream) {
    const float* atten = (const float*)d_in[0]; // (D,P,R)
    const float* rad   = (const float*)d_in[1]; // (D,P,R)
    const float* freq  = (const float*)d_in[2]; // (K,R)
    float* out = (float*)d_out;                 // (K,)
    float* ws  = (float*)d_ws;                  // needs 528 KiB

    k_reduce_p<<<D_DIRS / 4, 512, 0, stream>>>(atten, rad, ws);
    k_partial_m<<<NB_B, 256, 0, stream>>>(ws);
    k_csi<<<16, 256, 0, stream>>>(ws, freq, out);
}